// Round 15
// baseline (126826.526 us; speedup 1.0000x reference)
//
#include <hip/hip_runtime.h>
#include <stdint.h>

typedef unsigned long long u64;
typedef float f32x32 __attribute__((ext_vector_type(32)));
typedef float f32x16 __attribute__((ext_vector_type(16)));

#define T_TOTAL 65536
#define ISZ 256
#define HSZ 512
#define NWORK 16
#define SLICE 32   // HSZ / NWORK
#define NTHR 512   // 8 waves: even 2/SIMD split -> 256-reg budget (R10 lesson)

// LDS skew (word index): +4 words per row -> max 2-way bank aliasing (free).
__device__ __forceinline__ int HSW(int i) { return i + ((i >> 5) << 2); }  // rows of 32
__device__ __forceinline__ int XSW(int i) { return i + ((i >> 4) << 2); }  // rows of 16

struct Ctl { int grank; int chosen; int fastctr; int done; int slowctr; int pad[11]; };

// ---------------------------------------------------------------------------
// Persistent fused GRU scan, 16 blocks x 512 threads (R14 sync primitives:
// publish = plain 8B store (write-through vL1 -> XCD L2); poll = buffer_inv,
// waitcnt, L2 load — R14 proved correct+fast, WRITE_SIZE 1.1e7->1.3e5 KB).
//
// R14 -> R15: remove the remaining forced vmem drains from the chain:
//  - lane-role split: pollers (seg0-7; ONLY poll loads in queue, 2 slots ea),
//    x stagers (seg8-9; 2-step-deep reg pipeline so their HBM load is ~2
//    steps old at any wave-level vmcnt(0)), epilogue+publish+out (seg15;
//    fire-and-forget stores, never executes a vmem wait).
//  - raw s_barrier with lgkmcnt(0) ONLY (no __syncthreads vmcnt(0) drain).
//  - poller's first round issued speculatively BEFORE ig-dots (L2 RTT hides).
//
// Safety with ONE barrier (B2) per step, h_lds/x_lds parity double-buffered:
//  - h_lds[cur] rewrite at s+2 happens post-B2(s+1) in program order; B2 is a
//    block barrier, so all waves finished their step-s h_lds[cur] reads.
//  - x_lds[p] committed at step s (pre-B2(s)) is read at s+1 (post-B2(s));
//    next commit to p at s+2 is post-B2(s+1), after all s+1 reads.
//  - Inter-block slot overwrite gated by the tag protocol (R6/R8 argument).
// STICKY fallback per poller (64 stale rounds -> R8-proven sc0 RMW poll);
// SLOW fallback (election fails): R2-proven agent-scope tagged protocol.
// Spin fuse bounds worst-case runtime (fail visibly, never wedge).
// ---------------------------------------------------------------------------
__global__ __launch_bounds__(NTHR, 1) void gru_fused(
    const float* __restrict__ xs, const float* __restrict__ w_ih,
    const float* __restrict__ w_hh, const float* __restrict__ bias,
    const float* __restrict__ bias_n, u64* __restrict__ hslot,
    Ctl* __restrict__ ctl, float* __restrict__ out) {
  const int tid = threadIdx.x;
  const int seg = tid & 15;   // K-segment: h[32*seg..+32), x[16*seg..+16)
  const int rg  = tid >> 4;   // unit within slice (0..31)

  __shared__ int s_role, s_fast;
  __shared__ __align__(16) float x_lds[2][320];
  __shared__ __align__(16) float h_lds[2][576];

  // ---- election: verify 16 blocks on one XCD, else agent-scope fallback
  if (tid == 0) {
    unsigned xcc = 0;
    asm volatile("s_getreg_b32 %0, hwreg(HW_REG_XCC_ID)" : "=s"(xcc));
    long long eb = 100000000;
    int rank = __hip_atomic_fetch_add(&ctl->grank, 1, __ATOMIC_RELAXED,
                                      __HIP_MEMORY_SCOPE_AGENT);
    if (rank == 0)
      __hip_atomic_store(&ctl->chosen, (int)xcc + 1, __ATOMIC_RELEASE,
                         __HIP_MEMORY_SCOPE_AGENT);
    int chosen;
    do { chosen = __hip_atomic_load(&ctl->chosen, __ATOMIC_ACQUIRE,
                                    __HIP_MEMORY_SCOPE_AGENT); }
    while (chosen == 0 && --eb > 0);
    int fr = -1;
    if ((int)xcc == chosen - 1)
      fr = __hip_atomic_fetch_add(&ctl->fastctr, 1, __ATOMIC_RELAXED,
                                  __HIP_MEMORY_SCOPE_AGENT);
    __hip_atomic_fetch_add(&ctl->done, 1, __ATOMIC_ACQ_REL,
                           __HIP_MEMORY_SCOPE_AGENT);
    int dn;
    do { dn = __hip_atomic_load(&ctl->done, __ATOMIC_ACQUIRE,
                                __HIP_MEMORY_SCOPE_AGENT); }
    while (dn < (int)gridDim.x && --eb > 0);
    int fc = __hip_atomic_load(&ctl->fastctr, __ATOMIC_ACQUIRE,
                               __HIP_MEMORY_SCOPE_AGENT);
    int fast = (fc >= NWORK && dn >= (int)gridDim.x) ? 1 : 0;
    int role = -1;
    if (fast) {
      if (fr >= 0 && fr < NWORK) role = fr;
    } else {
      int sr = __hip_atomic_fetch_add(&ctl->slowctr, 1, __ATOMIC_RELAXED,
                                      __HIP_MEMORY_SCOPE_AGENT);
      if (sr < NWORK) role = sr;
    }
    s_role = role; s_fast = fast;
  }
  __syncthreads();
  const int role = s_role;   // uniform per block
  const int fast = s_fast;
  if (role < 0) return;      // whole block exits together

  // ---- weights into registers (ext_vector, static indexing; R8-proven) ----
  const int myunit = role * SLICE + rg;
  f32x32 wh0, wh1, wh2;
  f32x16 wi0, wi1, wi2;
  {
    const float* h0 = w_hh + (size_t)(0 * HSZ + myunit) * HSZ + seg * 32;
    const float* h1 = w_hh + (size_t)(1 * HSZ + myunit) * HSZ + seg * 32;
    const float* h2 = w_hh + (size_t)(2 * HSZ + myunit) * HSZ + seg * 32;
#pragma unroll
    for (int u = 0; u < 8; ++u) {
      float4 a = *(const float4*)(h0 + u * 4);
      float4 b = *(const float4*)(h1 + u * 4);
      float4 c = *(const float4*)(h2 + u * 4);
      wh0[u*4+0]=a.x; wh0[u*4+1]=a.y; wh0[u*4+2]=a.z; wh0[u*4+3]=a.w;
      wh1[u*4+0]=b.x; wh1[u*4+1]=b.y; wh1[u*4+2]=b.z; wh1[u*4+3]=b.w;
      wh2[u*4+0]=c.x; wh2[u*4+1]=c.y; wh2[u*4+2]=c.z; wh2[u*4+3]=c.w;
    }
    const float* i0 = w_ih + (size_t)(0 * HSZ + myunit) * ISZ + seg * 16;
    const float* i1 = w_ih + (size_t)(1 * HSZ + myunit) * ISZ + seg * 16;
    const float* i2 = w_ih + (size_t)(2 * HSZ + myunit) * ISZ + seg * 16;
#pragma unroll
    for (int u = 0; u < 4; ++u) {
      float4 a = *(const float4*)(i0 + u * 4);
      float4 b = *(const float4*)(i1 + u * 4);
      float4 c = *(const float4*)(i2 + u * 4);
      wi0[u*4+0]=a.x; wi0[u*4+1]=a.y; wi0[u*4+2]=a.z; wi0[u*4+3]=a.w;
      wi1[u*4+0]=b.x; wi1[u*4+1]=b.y; wi1[u*4+2]=b.z; wi1[u*4+3]=b.w;
      wi2[u*4+0]=c.x; wi2[u*4+1]=c.y; wi2[u*4+2]=c.z; wi2[u*4+3]=c.w;
    }
  }
  const float br  = bias[myunit];
  const float bz  = bias[HSZ + myunit];
  const float bnn = bias[2 * HSZ + myunit];
  const float bn2 = bias_n[myunit];

  long long budget = 20000000;  // spin fuse (fail visibly, never wedge)

  if (!fast) {
    // ---- SLOW fallback: R2-proven full-tag agent-scope protocol ----
    float hprev = 0.f;
    for (int s = 0; s < T_TOTAL; ++s) {
      if (tid < 64) {
        float4 v = *(const float4*)(xs + (size_t)s * ISZ + tid * 4);
        *(float4*)&x_lds[0][XSW(tid * 4)] = v;
      }
      __syncthreads();
      float a0 = 0.f, a1 = 0.f, a2 = 0.f, a3 = 0.f;
#pragma unroll
      for (int u = 0; u < 4; ++u) {
        float4 xv = *(const float4*)&x_lds[0][XSW(seg * 16 + u * 4)];
        a0 += wi0[u*4+0]*xv.x + wi0[u*4+1]*xv.y + wi0[u*4+2]*xv.z + wi0[u*4+3]*xv.w;
        a1 += wi1[u*4+0]*xv.x + wi1[u*4+1]*xv.y + wi1[u*4+2]*xv.z + wi1[u*4+3]*xv.w;
        a2 += wi2[u*4+0]*xv.x + wi2[u*4+1]*xv.y + wi2[u*4+2]*xv.z + wi2[u*4+3]*xv.w;
      }
      const int cur = s & 1, nxt = cur ^ 1;
      u64 q0;
      do {
        q0 = __hip_atomic_load(&hslot[(size_t)cur * 1024 + 2 * tid],
                               __ATOMIC_ACQUIRE, __HIP_MEMORY_SCOPE_AGENT);
      } while ((unsigned)(q0 >> 32) != (unsigned)s && --budget > 0);
      h_lds[cur][HSW(tid)] = __uint_as_float((unsigned)q0);
      __syncthreads();
#pragma unroll
      for (int u = 0; u < 8; ++u) {
        float4 hv = *(const float4*)&h_lds[cur][HSW(seg * 32 + u * 4)];
        a0 += wh0[u*4+0]*hv.x + wh0[u*4+1]*hv.y + wh0[u*4+2]*hv.z + wh0[u*4+3]*hv.w;
        a1 += wh1[u*4+0]*hv.x + wh1[u*4+1]*hv.y + wh1[u*4+2]*hv.z + wh1[u*4+3]*hv.w;
        a3 += wh2[u*4+0]*hv.x + wh2[u*4+1]*hv.y + wh2[u*4+2]*hv.z + wh2[u*4+3]*hv.w;
      }
#pragma unroll
      for (int p = 0; p < 4; ++p) {
        int m = 1 << p;
        a0 += __shfl_xor(a0, m, 64);
        a1 += __shfl_xor(a1, m, 64);
        a2 += __shfl_xor(a2, m, 64);
        a3 += __shfl_xor(a3, m, 64);
      }
      if (seg == 0) {
        float r  = 1.f / (1.f + __expf(-(br + a0)));
        float z  = 1.f / (1.f + __expf(-(bz + a1)));
        float tv = bnn + a2 + r * (a3 + bn2);
        float nn = 1.f - 2.f / (__expf(2.f * tv) + 1.f);
        float hold = h_lds[cur][HSW(myunit)];
        float hnew = nn + z * (hold - nn);
        __hip_atomic_store(&hslot[(size_t)nxt * 1024 + 2 * myunit],
                           ((u64)(unsigned)(s + 1) << 32) | (u64)__float_as_uint(hnew),
                           __ATOMIC_RELEASE, __HIP_MEMORY_SCOPE_AGENT);
        out[(size_t)HSZ + (size_t)s * HSZ + myunit] = hnew;
        hprev = hnew;
      }
      __syncthreads();
    }
    if (seg == 0) out[myunit] = hprev;
    return;
  }

  // ---- FAST path ----
  const bool is_poll = (seg < 8);
  const int  pollid  = rg * 8 + seg;            // 0..255 (2 slots each)
  const bool is_stg  = (seg == 8) || (seg == 9);
  const int  st      = rg * 2 + (seg - 8);      // 0..63 for stagers

  // Prologue: stagers put x[0] in LDS buf0; xA=x[1], xB=x[2] (2-deep pipe).
  float4 xA{}, xB{};
  if (is_stg) {
    float4 t0 = *(const float4*)(xs + st * 4);
    *(float4*)&x_lds[0][XSW(st * 4)] = t0;
    xA = *(const float4*)(xs + (size_t)1 * ISZ + st * 4);
    xB = *(const float4*)(xs + (size_t)2 * ISZ + st * 4);
  }
  __syncthreads();

  int sticky = 0;

  for (int s = 0; s < T_TOTAL; ++s) {
    const int cur = s & 1, nxt = cur ^ 1;

    // 1) Pollers: speculative first round issued BEFORE ig-dots.
    u64 q0 = 0, q1 = 0;
    u64* sb = hslot + (size_t)cur * 1024;
    if (is_poll && !sticky) {
      const u64* p0 = sb + 4 * pollid;
      const u64* p1 = sb + 4 * pollid + 2;
      asm volatile("buffer_inv\n\t"
                   "s_waitcnt vmcnt(0)\n\t"
                   "global_load_dwordx2 %0, %2, off sc0 nt\n\t"
                   "global_load_dwordx2 %1, %3, off sc0 nt"
                   : "=&v"(q0), "=&v"(q1) : "v"(p0), "v"(p1) : "memory");
    }

    // 2) All lanes: input-side gate dots (LDS only; hides the L2 RTT).
    float a0 = 0.f, a1 = 0.f, a2 = 0.f, a3 = 0.f;
#pragma unroll
    for (int u = 0; u < 4; ++u) {
      float4 xv = *(const float4*)&x_lds[cur][XSW(seg * 16 + u * 4)];
      a0 += wi0[u*4+0]*xv.x + wi0[u*4+1]*xv.y + wi0[u*4+2]*xv.z + wi0[u*4+3]*xv.w;
      a1 += wi1[u*4+0]*xv.x + wi1[u*4+1]*xv.y + wi1[u*4+2]*xv.z + wi1[u*4+3]*xv.w;
      a2 += wi2[u*4+0]*xv.x + wi2[u*4+1]*xv.y + wi2[u*4+2]*xv.z + wi2[u*4+3]*xv.w;
    }

    // 3) Pollers: complete/iterate the poll. Their queue holds ONLY these
    //    loads, so vmcnt(0) waits one L2 RTT — no HBM drain on the chain.
    if (is_poll) {
      const u64* p0 = sb + 4 * pollid;
      const u64* p1 = sb + 4 * pollid + 2;
      if (!sticky) {
        asm volatile("s_waitcnt vmcnt(0)" ::: "memory");
        int rounds = 0;
        while (((unsigned)(q0 >> 32) != (unsigned)s) |
               ((unsigned)(q1 >> 32) != (unsigned)s)) {
          asm volatile("buffer_inv\n\t"
                       "s_waitcnt vmcnt(0)\n\t"
                       "global_load_dwordx2 %0, %2, off sc0 nt\n\t"
                       "global_load_dwordx2 %1, %3, off sc0 nt\n\t"
                       "s_waitcnt vmcnt(0)"
                       : "=&v"(q0), "=&v"(q1) : "v"(p0), "v"(p1) : "memory");
          if (++rounds >= 64) { sticky = 1; break; }
          if (--budget <= 0) break;
        }
      }
      if (sticky) {  // R8-proven TCC RMW poll (safety net; slower, correct)
        u64 zero = 0;
        for (;;) {
          asm volatile("global_atomic_add_x2 %0, %2, %4, off sc0\n\t"
                       "global_atomic_add_x2 %1, %3, %4, off sc0\n\t"
                       "s_waitcnt vmcnt(0)"
                       : "=&v"(q0), "=&v"(q1)
                       : "v"((u64*)p0), "v"((u64*)p1), "v"(zero)
                       : "memory");
          if (((unsigned)(q0 >> 32) == (unsigned)s) &
              ((unsigned)(q1 >> 32) == (unsigned)s)) break;
          if (--budget <= 0) break;
        }
      }
      float2 hv2;
      hv2.x = __uint_as_float((unsigned)q0);
      hv2.y = __uint_as_float((unsigned)q1);
      *(float2*)&h_lds[cur][HSW(2 * pollid)] = hv2;
    }

    // 4) Stagers: commit x[s+1] (loaded 2 steps ago), issue x[s+3].
    if (is_stg) {
      int srow = (s + 3 < T_TOTAL) ? (s + 3) : (T_TOTAL - 1);
      if ((s & 1) == 0) {
        *(float4*)&x_lds[nxt][XSW(st * 4)] = xA;
        xA = *(const float4*)(xs + (size_t)srow * ISZ + st * 4);
      } else {
        *(float4*)&x_lds[nxt][XSW(st * 4)] = xB;
        xB = *(const float4*)(xs + (size_t)srow * ISZ + st * 4);
      }
    }

    // B2: LDS-only barrier (NO vmcnt drain — the R14 chain killer).
    asm volatile("s_waitcnt lgkmcnt(0)\n\ts_barrier" ::: "memory");

    // 5) Hidden-side dots (critical chain) + butterfly (sums land in ALL lanes).
#pragma unroll
    for (int u = 0; u < 8; ++u) {
      float4 hv = *(const float4*)&h_lds[cur][HSW(seg * 32 + u * 4)];
      a0 += wh0[u*4+0]*hv.x + wh0[u*4+1]*hv.y + wh0[u*4+2]*hv.z + wh0[u*4+3]*hv.w;
      a1 += wh1[u*4+0]*hv.x + wh1[u*4+1]*hv.y + wh1[u*4+2]*hv.z + wh1[u*4+3]*hv.w;
      a3 += wh2[u*4+0]*hv.x + wh2[u*4+1]*hv.y + wh2[u*4+2]*hv.z + wh2[u*4+3]*hv.w;
    }
#pragma unroll
    for (int p = 0; p < 4; ++p) {
      int m = 1 << p;
      a0 += __shfl_xor(a0, m, 64);
      a1 += __shfl_xor(a1, m, 64);
      a2 += __shfl_xor(a2, m, 64);
      a3 += __shfl_xor(a3, m, 64);
    }

    // 6) Epilogue on seg15 (a NON-poller lane): publish (L2, fire-and-forget)
    //    then out store (HBM, fire-and-forget). This lane never vmem-waits.
    if (seg == 15) {
      float r  = 1.f / (1.f + __expf(-(br + a0)));
      float z  = 1.f / (1.f + __expf(-(bz + a1)));
      float tv = bnn + a2 + r * (a3 + bn2);
      float nn = 1.f - 2.f / (__expf(2.f * tv) + 1.f);  // tanh, exact limits
      float hold = h_lds[cur][HSW(myunit)];
      float hnew = nn + z * (hold - nn);
      u64 pw = ((u64)(unsigned)(s + 1) << 32) | (u64)__float_as_uint(hnew);
      u64* pp = &hslot[(size_t)nxt * 1024 + 2 * myunit];
      asm volatile("global_store_dwordx2 %0, %1, off" :: "v"(pp), "v"(pw) : "memory");
      out[(size_t)HSZ + (size_t)s * HSZ + myunit] = hnew;
      if (s == T_TOTAL - 1) out[myunit] = hnew;
    }
  }
}

// ---------------------------------------------------------------------------
extern "C" void kernel_launch(void* const* d_in, const int* in_sizes, int n_in,
                              void* d_out, int out_size, void* d_ws, size_t ws_size,
                              hipStream_t stream) {
  const float* xs     = (const float*)d_in[0];
  const float* w_ih   = (const float*)d_in[1];
  const float* w_hh   = (const float*)d_in[2];
  const float* bias   = (const float*)d_in[3];
  const float* bias_n = (const float*)d_in[4];
  float* out   = (float*)d_out;
  u64*   hslot = (u64*)d_ws;                    // [2][1024] padded slots = 16 KB
  Ctl*   ctl   = (Ctl*)((char*)d_ws + 16384);   // election control

  hipMemsetAsync(d_ws, 0, 16384 + 256, stream); // tags=0 => h_0 = 0; ctl = 0
  gru_fused<<<256, NTHR, 0, stream>>>(xs, w_ih, w_hh, bias, bias_n, hslot, ctl, out);
}

// Round 16
// 122639.087 us; speedup vs baseline: 1.0341x; 1.0341x over previous
//
#include <hip/hip_runtime.h>
#include <stdint.h>

typedef unsigned long long u64;
typedef float f32x32 __attribute__((ext_vector_type(32)));
typedef float f32x16 __attribute__((ext_vector_type(16)));
typedef float f32x4  __attribute__((ext_vector_type(4)));

#define T_TOTAL 65536
#define ISZ 256
#define HSZ 512
#define NWORK 16
#define SLICE 32   // HSZ / NWORK
#define NTHR 512   // 8 waves: even 2/SIMD split -> 256-reg budget (R10 lesson)

// LDS skew (word index): +4 words per row -> max 2-way bank aliasing (free).
__device__ __forceinline__ int HSW(int i) { return i + ((i >> 5) << 2); }  // rows of 32
__device__ __forceinline__ int XSW(int i) { return i + ((i >> 4) << 2); }  // rows of 16

struct Ctl { int grank; int chosen; int fastctr; int done; int slowctr; int pad[11]; };

// asm x-load: issue only; completion managed by counted vmcnt in wave 7.
__device__ __forceinline__ f32x4 xload_asm(const float* p) {
  f32x4 r;
  asm volatile("global_load_dwordx4 %0, %1, off" : "=v"(r) : "v"(p));
  return r;
}

// ---------------------------------------------------------------------------
// Persistent fused GRU scan, 16 blocks x 512 threads.
// Sync primitives (R14-proven): publish = plain 8B store (write-through vL1
// -> XCD L2); poll = buffer_inv; waitcnt; L2 load (sticky RMW fallback).
//
// R15 -> R16: role split at WAVE granularity (vmcnt is per-wave; R15's
// lane-level split put HBM x-loads in every wave's queue -> every poll
// vmcnt(0) drained HBM; 98->127ms regression):
//   waves 0-3: pollers only (queue = 2 L2 poll loads; vmcnt(0) = L2 RTT)
//   waves 4-6: pure compute (no vmem in steady state)
//   wave 7:    x stager (2-deep asm reg pipeline, counted vmcnt: per-step
//              vmem = {xload,pub,out}=3 ops, so x(s-2) has 5 younger ops ->
//              s_waitcnt vmcnt(5); steps 0/1 use vmcnt(1)/vmcnt(3)) and
//              publisher (hq LDS handoff; 32 pub + 32 out stores, asm,
//              fire-and-forget). No wave ever drains HBM on the chain.
// Barriers: B2 (h+x staged) and B3 (hq ready), both raw s_barrier with
// lgkmcnt(0) only (no __syncthreads vmcnt drain).
//
// Safety: h_lds[cur] rewrite at s+2 is post-B3(s+1) >= B3(s) >= all waves'
// matvec(s) reads. x_lds[nxt] commit(s) pre-B2(s) < reads(s+1) pre-B2(s+1)
// < next commit(s+2) post-B2(s+1). hq write(s) pre-B3(s) < read(s) post-
// B3(s) < rewrite(s+1) post-B2(s+1). Inter-block slot overwrite: A publishes
// tag s+1 only after A's B2(s) saw tag s everywhere; tag s from block D
// implies D passed B3(s-1), i.e. D's pollers finished reading tag s-1.
// Spin fuse (fail visibly, never wedge); SLOW fallback: R2-proven protocol.
// ---------------------------------------------------------------------------
__global__ __launch_bounds__(NTHR, 1) void gru_fused(
    const float* __restrict__ xs, const float* __restrict__ w_ih,
    const float* __restrict__ w_hh, const float* __restrict__ bias,
    const float* __restrict__ bias_n, u64* __restrict__ hslot,
    Ctl* __restrict__ ctl, float* __restrict__ out) {
  const int tid = threadIdx.x;
  const int seg = tid & 15;   // K-segment: h[32*seg..+32), x[16*seg..+16)
  const int rg  = tid >> 4;   // unit within slice (0..31)

  __shared__ int s_role, s_fast;
  __shared__ __align__(16) float x_lds[2][320];
  __shared__ __align__(16) float h_lds[2][576];
  __shared__ __align__(16) float hq[32];

  // ---- election: verify 16 blocks on one XCD, else agent-scope fallback
  if (tid == 0) {
    unsigned xcc = 0;
    asm volatile("s_getreg_b32 %0, hwreg(HW_REG_XCC_ID)" : "=s"(xcc));
    long long eb = 100000000;
    int rank = __hip_atomic_fetch_add(&ctl->grank, 1, __ATOMIC_RELAXED,
                                      __HIP_MEMORY_SCOPE_AGENT);
    if (rank == 0)
      __hip_atomic_store(&ctl->chosen, (int)xcc + 1, __ATOMIC_RELEASE,
                         __HIP_MEMORY_SCOPE_AGENT);
    int chosen;
    do { chosen = __hip_atomic_load(&ctl->chosen, __ATOMIC_ACQUIRE,
                                    __HIP_MEMORY_SCOPE_AGENT); }
    while (chosen == 0 && --eb > 0);
    int fr = -1;
    if ((int)xcc == chosen - 1)
      fr = __hip_atomic_fetch_add(&ctl->fastctr, 1, __ATOMIC_RELAXED,
                                  __HIP_MEMORY_SCOPE_AGENT);
    __hip_atomic_fetch_add(&ctl->done, 1, __ATOMIC_ACQ_REL,
                           __HIP_MEMORY_SCOPE_AGENT);
    int dn;
    do { dn = __hip_atomic_load(&ctl->done, __ATOMIC_ACQUIRE,
                                __HIP_MEMORY_SCOPE_AGENT); }
    while (dn < (int)gridDim.x && --eb > 0);
    int fc = __hip_atomic_load(&ctl->fastctr, __ATOMIC_ACQUIRE,
                               __HIP_MEMORY_SCOPE_AGENT);
    int fast = (fc >= NWORK && dn >= (int)gridDim.x) ? 1 : 0;
    int role = -1;
    if (fast) {
      if (fr >= 0 && fr < NWORK) role = fr;
    } else {
      int sr = __hip_atomic_fetch_add(&ctl->slowctr, 1, __ATOMIC_RELAXED,
                                      __HIP_MEMORY_SCOPE_AGENT);
      if (sr < NWORK) role = sr;
    }
    s_role = role; s_fast = fast;
  }
  __syncthreads();
  const int role = s_role;   // uniform per block
  const int fast = s_fast;
  if (role < 0) return;      // whole block exits together

  // ---- weights into registers (ext_vector, static indexing; R8-proven) ----
  const int myunit = role * SLICE + rg;
  f32x32 wh0, wh1, wh2;
  f32x16 wi0, wi1, wi2;
  {
    const float* h0 = w_hh + (size_t)(0 * HSZ + myunit) * HSZ + seg * 32;
    const float* h1 = w_hh + (size_t)(1 * HSZ + myunit) * HSZ + seg * 32;
    const float* h2 = w_hh + (size_t)(2 * HSZ + myunit) * HSZ + seg * 32;
#pragma unroll
    for (int u = 0; u < 8; ++u) {
      float4 a = *(const float4*)(h0 + u * 4);
      float4 b = *(const float4*)(h1 + u * 4);
      float4 c = *(const float4*)(h2 + u * 4);
      wh0[u*4+0]=a.x; wh0[u*4+1]=a.y; wh0[u*4+2]=a.z; wh0[u*4+3]=a.w;
      wh1[u*4+0]=b.x; wh1[u*4+1]=b.y; wh1[u*4+2]=b.z; wh1[u*4+3]=b.w;
      wh2[u*4+0]=c.x; wh2[u*4+1]=c.y; wh2[u*4+2]=c.z; wh2[u*4+3]=c.w;
    }
    const float* i0 = w_ih + (size_t)(0 * HSZ + myunit) * ISZ + seg * 16;
    const float* i1 = w_ih + (size_t)(1 * HSZ + myunit) * ISZ + seg * 16;
    const float* i2 = w_ih + (size_t)(2 * HSZ + myunit) * ISZ + seg * 16;
#pragma unroll
    for (int u = 0; u < 4; ++u) {
      float4 a = *(const float4*)(i0 + u * 4);
      float4 b = *(const float4*)(i1 + u * 4);
      float4 c = *(const float4*)(i2 + u * 4);
      wi0[u*4+0]=a.x; wi0[u*4+1]=a.y; wi0[u*4+2]=a.z; wi0[u*4+3]=a.w;
      wi1[u*4+0]=b.x; wi1[u*4+1]=b.y; wi1[u*4+2]=b.z; wi1[u*4+3]=b.w;
      wi2[u*4+0]=c.x; wi2[u*4+1]=c.y; wi2[u*4+2]=c.z; wi2[u*4+3]=c.w;
    }
  }
  const float br  = bias[myunit];
  const float bz  = bias[HSZ + myunit];
  const float bnn = bias[2 * HSZ + myunit];
  const float bn2 = bias_n[myunit];

  long long budget = 20000000;  // spin fuse (fail visibly, never wedge)

  if (!fast) {
    // ---- SLOW fallback: R2-proven full-tag agent-scope protocol ----
    float hprev = 0.f;
    for (int s = 0; s < T_TOTAL; ++s) {
      if (tid < 64) {
        float4 v = *(const float4*)(xs + (size_t)s * ISZ + tid * 4);
        *(float4*)&x_lds[0][XSW(tid * 4)] = v;
      }
      __syncthreads();
      float a0 = 0.f, a1 = 0.f, a2 = 0.f, a3 = 0.f;
#pragma unroll
      for (int u = 0; u < 4; ++u) {
        float4 xv = *(const float4*)&x_lds[0][XSW(seg * 16 + u * 4)];
        a0 += wi0[u*4+0]*xv.x + wi0[u*4+1]*xv.y + wi0[u*4+2]*xv.z + wi0[u*4+3]*xv.w;
        a1 += wi1[u*4+0]*xv.x + wi1[u*4+1]*xv.y + wi1[u*4+2]*xv.z + wi1[u*4+3]*xv.w;
        a2 += wi2[u*4+0]*xv.x + wi2[u*4+1]*xv.y + wi2[u*4+2]*xv.z + wi2[u*4+3]*xv.w;
      }
      const int cur = s & 1, nxt = cur ^ 1;
      u64 q0;
      do {
        q0 = __hip_atomic_load(&hslot[(size_t)cur * 1024 + 2 * tid],
                               __ATOMIC_ACQUIRE, __HIP_MEMORY_SCOPE_AGENT);
      } while ((unsigned)(q0 >> 32) != (unsigned)s && --budget > 0);
      h_lds[cur][HSW(tid)] = __uint_as_float((unsigned)q0);
      __syncthreads();
#pragma unroll
      for (int u = 0; u < 8; ++u) {
        float4 hv = *(const float4*)&h_lds[cur][HSW(seg * 32 + u * 4)];
        a0 += wh0[u*4+0]*hv.x + wh0[u*4+1]*hv.y + wh0[u*4+2]*hv.z + wh0[u*4+3]*hv.w;
        a1 += wh1[u*4+0]*hv.x + wh1[u*4+1]*hv.y + wh1[u*4+2]*hv.z + wh1[u*4+3]*hv.w;
        a3 += wh2[u*4+0]*hv.x + wh2[u*4+1]*hv.y + wh2[u*4+2]*hv.z + wh2[u*4+3]*hv.w;
      }
#pragma unroll
      for (int p = 0; p < 4; ++p) {
        int m = 1 << p;
        a0 += __shfl_xor(a0, m, 64);
        a1 += __shfl_xor(a1, m, 64);
        a2 += __shfl_xor(a2, m, 64);
        a3 += __shfl_xor(a3, m, 64);
      }
      if (seg == 0) {
        float r  = 1.f / (1.f + __expf(-(br + a0)));
        float z  = 1.f / (1.f + __expf(-(bz + a1)));
        float tv = bnn + a2 + r * (a3 + bn2);
        float nn = 1.f - 2.f / (__expf(2.f * tv) + 1.f);
        float hold = h_lds[cur][HSW(myunit)];
        float hnew = nn + z * (hold - nn);
        __hip_atomic_store(&hslot[(size_t)nxt * 1024 + 2 * myunit],
                           ((u64)(unsigned)(s + 1) << 32) | (u64)__float_as_uint(hnew),
                           __ATOMIC_RELEASE, __HIP_MEMORY_SCOPE_AGENT);
        out[(size_t)HSZ + (size_t)s * HSZ + myunit] = hnew;
        hprev = hnew;
      }
      __syncthreads();
    }
    if (seg == 0) out[myunit] = hprev;
    return;
  }

  // ---- FAST path: wave-granular roles ----
  const bool is_poll = (tid < 256);          // waves 0-3
  const bool is_w7   = (tid >= 448);         // wave 7
  const int  wl      = tid - 448;            // wave-7 lane 0..63

  // Prologue (wave 7): x[0] -> LDS (compiler-managed load); issue x[1], x[2].
  f32x4 xA{}, xB{};
  if (is_w7) {
    float4 t0 = *(const float4*)(xs + wl * 4);
    *(float4*)&x_lds[0][XSW(wl * 4)] = t0;
    xA = xload_asm(xs + (size_t)1 * ISZ + wl * 4);
    xB = xload_asm(xs + (size_t)2 * ISZ + wl * 4);
  }
  __syncthreads();

  int sticky = 0;

  for (int s = 0; s < T_TOTAL; ++s) {
    const int cur = s & 1, nxt = cur ^ 1;

    // 1) Pollers: speculative first round BEFORE ig-dots (L2 RTT hides).
    u64 q0 = 0, q1 = 0;
    u64* sb = hslot + (size_t)cur * 1024;
    if (is_poll && !sticky) {
      const u64* p0 = sb + 4 * tid;
      const u64* p1 = sb + 4 * tid + 2;
      asm volatile("buffer_inv\n\t"
                   "s_waitcnt vmcnt(0)\n\t"
                   "global_load_dwordx2 %0, %2, off sc0 nt\n\t"
                   "global_load_dwordx2 %1, %3, off sc0 nt"
                   : "=&v"(q0), "=&v"(q1) : "v"(p0), "v"(p1) : "memory");
    }

    // 2) All lanes: input-side gate dots (LDS only).
    float a0 = 0.f, a1 = 0.f, a2 = 0.f, a3 = 0.f;
#pragma unroll
    for (int u = 0; u < 4; ++u) {
      float4 xv = *(const float4*)&x_lds[cur][XSW(seg * 16 + u * 4)];
      a0 += wi0[u*4+0]*xv.x + wi0[u*4+1]*xv.y + wi0[u*4+2]*xv.z + wi0[u*4+3]*xv.w;
      a1 += wi1[u*4+0]*xv.x + wi1[u*4+1]*xv.y + wi1[u*4+2]*xv.z + wi1[u*4+3]*xv.w;
      a2 += wi2[u*4+0]*xv.x + wi2[u*4+1]*xv.y + wi2[u*4+2]*xv.z + wi2[u*4+3]*xv.w;
    }

    // 3) Pollers: finish/iterate. Queue holds ONLY poll loads -> vmcnt(0)
    //    is one L2 RTT, never an HBM drain.
    if (is_poll) {
      const u64* p0 = sb + 4 * tid;
      const u64* p1 = sb + 4 * tid + 2;
      if (!sticky) {
        asm volatile("s_waitcnt vmcnt(0)" ::: "memory");
        int rounds = 0;
        while (((unsigned)(q0 >> 32) != (unsigned)s) |
               ((unsigned)(q1 >> 32) != (unsigned)s)) {
          asm volatile("buffer_inv\n\t"
                       "s_waitcnt vmcnt(0)\n\t"
                       "global_load_dwordx2 %0, %2, off sc0 nt\n\t"
                       "global_load_dwordx2 %1, %3, off sc0 nt\n\t"
                       "s_waitcnt vmcnt(0)"
                       : "=&v"(q0), "=&v"(q1) : "v"(p0), "v"(p1) : "memory");
          if (++rounds >= 64) { sticky = 1; break; }
          if (--budget <= 0) break;
        }
      }
      if (sticky) {  // R8-proven TCC RMW poll (correctness safety net)
        u64 zero = 0;
        for (;;) {
          asm volatile("global_atomic_add_x2 %0, %2, %4, off sc0\n\t"
                       "global_atomic_add_x2 %1, %3, %4, off sc0\n\t"
                       "s_waitcnt vmcnt(0)"
                       : "=&v"(q0), "=&v"(q1)
                       : "v"((u64*)p0), "v"((u64*)p1), "v"(zero)
                       : "memory");
          if (((unsigned)(q0 >> 32) == (unsigned)s) &
              ((unsigned)(q1 >> 32) == (unsigned)s)) break;
          if (--budget <= 0) break;
        }
      }
      float2 hv2;
      hv2.x = __uint_as_float((unsigned)q0);
      hv2.y = __uint_as_float((unsigned)q1);
      *(float2*)&h_lds[cur][HSW(2 * tid)] = hv2;
    }

    // 4) Wave 7: commit x[s+1] (2 steps old; counted vmcnt — per step this
    //    wave issues {xload, pub, out} = 3 vmem ops, so x(s-2) has exactly 5
    //    younger ops -> vmcnt(5) retires it; s=0/1 peeled counts), then
    //    issue x[s+3]. Never vmcnt(0) in steady state.
    if (is_w7) {
      if (s == 0)      asm volatile("s_waitcnt vmcnt(1)" ::: "memory");
      else if (s == 1) asm volatile("s_waitcnt vmcnt(3)" ::: "memory");
      else             asm volatile("s_waitcnt vmcnt(5)" ::: "memory");
      int srow = (s + 3 < T_TOTAL) ? (s + 3) : (T_TOTAL - 1);
      if ((s & 1) == 0) {
        *(f32x4*)&x_lds[nxt][XSW(wl * 4)] = xA;
        xA = xload_asm(xs + (size_t)srow * ISZ + wl * 4);
      } else {
        *(f32x4*)&x_lds[nxt][XSW(wl * 4)] = xB;
        xB = xload_asm(xs + (size_t)srow * ISZ + wl * 4);
      }
    }

    // B2: LDS-only barrier (no vmcnt drain).
    asm volatile("s_waitcnt lgkmcnt(0)\n\ts_barrier" ::: "memory");

    // 5) Hidden-side dots (critical chain) + butterfly (sums in all 16 lanes).
#pragma unroll
    for (int u = 0; u < 8; ++u) {
      float4 hv = *(const float4*)&h_lds[cur][HSW(seg * 32 + u * 4)];
      a0 += wh0[u*4+0]*hv.x + wh0[u*4+1]*hv.y + wh0[u*4+2]*hv.z + wh0[u*4+3]*hv.w;
      a1 += wh1[u*4+0]*hv.x + wh1[u*4+1]*hv.y + wh1[u*4+2]*hv.z + wh1[u*4+3]*hv.w;
      a3 += wh2[u*4+0]*hv.x + wh2[u*4+1]*hv.y + wh2[u*4+2]*hv.z + wh2[u*4+3]*hv.w;
    }
#pragma unroll
    for (int p = 0; p < 4; ++p) {
      int m = 1 << p;
      a0 += __shfl_xor(a0, m, 64);
      a1 += __shfl_xor(a1, m, 64);
      a2 += __shfl_xor(a2, m, 64);
      a3 += __shfl_xor(a3, m, 64);
    }

    // 6) Epilogue on seg15 -> hq (LDS only; no vmem in compute waves).
    if (seg == 15) {
      float r  = 1.f / (1.f + __expf(-(br + a0)));
      float z  = 1.f / (1.f + __expf(-(bz + a1)));
      float tv = bnn + a2 + r * (a3 + bn2);
      float nn = 1.f - 2.f / (__expf(2.f * tv) + 1.f);  // tanh, exact limits
      float hold = h_lds[cur][HSW(myunit)];
      hq[rg] = nn + z * (hold - nn);
    }

    // B3: hq ready (lgkm-only barrier).
    asm volatile("s_waitcnt lgkmcnt(0)\n\ts_barrier" ::: "memory");

    // 7) Wave 7 lanes 0-31: publish (L2, chain edge) then out store (both
    //    asm fire-and-forget; this wave only ever waits counted vmcnt).
    if (is_w7 && wl < 32) {
      float hv = hq[wl];
      u64 pw = ((u64)(unsigned)(s + 1) << 32) | (u64)__float_as_uint(hv);
      u64* pp = &hslot[(size_t)nxt * 1024 + 2 * (role * SLICE + wl)];
      asm volatile("global_store_dwordx2 %0, %1, off" :: "v"(pp), "v"(pw) : "memory");
      float* po = out + HSZ + (size_t)s * HSZ + role * SLICE + wl;
      asm volatile("global_store_dword %0, %1, off" :: "v"(po), "v"(hv) : "memory");
      if (s == T_TOTAL - 1) {
        float* pf = out + role * SLICE + wl;
        asm volatile("global_store_dword %0, %1, off" :: "v"(pf), "v"(hv) : "memory");
      }
    }
  }
}

// ---------------------------------------------------------------------------
extern "C" void kernel_launch(void* const* d_in, const int* in_sizes, int n_in,
                              void* d_out, int out_size, void* d_ws, size_t ws_size,
                              hipStream_t stream) {
  const float* xs     = (const float*)d_in[0];
  const float* w_ih   = (const float*)d_in[1];
  const float* w_hh   = (const float*)d_in[2];
  const float* bias   = (const float*)d_in[3];
  const float* bias_n = (const float*)d_in[4];
  float* out   = (float*)d_out;
  u64*   hslot = (u64*)d_ws;                    // [2][1024] padded slots = 16 KB
  Ctl*   ctl   = (Ctl*)((char*)d_ws + 16384);   // election control

  hipMemsetAsync(d_ws, 0, 16384 + 256, stream); // tags=0 => h_0 = 0; ctl = 0
  gru_fused<<<256, NTHR, 0, stream>>>(xs, w_ih, w_hh, bias, bias_n, hslot, ctl, out);
}